// Round 6
// baseline (2144.318 us; speedup 1.0000x reference)
//
#include <hip/hip_runtime.h>
#include <hip/hip_bf16.h>

// MultiheadAttention (heads=1): B=4, N=4096, D=512, PROJ=512. scale=0.125.
// Inputs fp32, output fp32. Internal: bf16 MFMA, fp32 accum.
//
// R6: flash restructured for 2 blocks/CU (the lever all prior rounds lacked):
//  - key-split 2-way across blocks: grid (64 qtiles, 4 batch, 2 key-halves) = 512 blocks
//  - per-wave Q = 32 rows x k-quarter (32 VGPR): K-frag dup 1; S partials summed
//    via LDS atomicAdd (ds_add_f32), zeroed during softmax read-out
//  - Tk=32, 5 barriers/chunk; K(j+1) prefetched via VGPR path during softmax/PV
//  - LDS 68KB, __launch_bounds__(512,4) -> 2 blocks/CU so barrier drains overlap
//  - merge kernel combines the two key-half partials (bf16 O~, fp32 m/l)

typedef __attribute__((ext_vector_type(8))) short bf16x8;
typedef __attribute__((ext_vector_type(4))) float f32x4;

#define NB 4
#define NN 4096
#define ND 512

__device__ __forceinline__ f32x4 mfma16(bf16x8 a, bf16x8 b, f32x4 c) {
    return __builtin_amdgcn_mfma_f32_16x16x32_bf16(a, b, c, 0, 0, 0);
}
__device__ __forceinline__ short f2bf(float f) {
    __hip_bfloat16 h = __float2bfloat16(f);
    return *reinterpret_cast<short*>(&h);
}
__device__ __forceinline__ float bf2f(short s) {
    __hip_bfloat16 h;
    *reinterpret_cast<short*>(&h) = s;
    return __bfloat162float(h);
}

// ---------------- weight transpose: Wt[c][r] (bf16) = W[r][c] (fp32), 512x512 ----
struct Ptrs4 {
    const float* in[4];
    short* out[4];
};

__global__ void transpose_w(Ptrs4 p) {
    __shared__ short tile[32][33];
    const float* in = p.in[blockIdx.z];
    short* out = p.out[blockIdx.z];
    int r0 = blockIdx.y * 32, c0 = blockIdx.x * 32;
    int tx = threadIdx.x, ty = threadIdx.y;  // 32 x 8
    for (int i = 0; i < 32; i += 8)
        tile[ty + i][tx] = f2bf(in[(r0 + ty + i) * 512 + c0 + tx]);
    __syncthreads();
    for (int i = 0; i < 32; i += 8)
        out[(c0 + ty + i) * 512 + r0 + tx] = tile[tx][ty + i];
}

// ---------------- bt-form GEMM + bias, 128x128 tile, BK=64 (unchanged from R4) ----
template <int AF32, int VT, int OF32>
__global__ __launch_bounds__(256, 2) void gemm_bt_bias(
    const void* __restrict__ Av, const short* __restrict__ Bt,
    const float* __restrict__ bias, void* __restrict__ C) {
    __shared__ short As[128][72];
    __shared__ short Bs[128][72];
    int tid = threadIdx.x;
    int lane = tid & 63, w = tid >> 6;
    int l15 = lane & 15, l4 = lane >> 4;
    int wm = w & 1, wn = w >> 1;
    int m0 = blockIdx.y * 128, n0 = blockIdx.x * 128;
    f32x4 acc[4][4] = {};
    for (int kt = 0; kt < 512; kt += 64) {
        __syncthreads();
#pragma unroll
        for (int i = 0; i < 4; i++) {
            int vv = tid + i * 256;
            int row = vv >> 3, col8 = (vv & 7) * 8;
            if (AF32) {
                const float* A = (const float*)Av;
                const float* src = &A[(size_t)(m0 + row) * 512 + kt + col8];
                float4 f0 = *(const float4*)src;
                float4 f1 = *(const float4*)(src + 4);
                short tmp[8];
                tmp[0] = f2bf(f0.x); tmp[1] = f2bf(f0.y);
                tmp[2] = f2bf(f0.z); tmp[3] = f2bf(f0.w);
                tmp[4] = f2bf(f1.x); tmp[5] = f2bf(f1.y);
                tmp[6] = f2bf(f1.z); tmp[7] = f2bf(f1.w);
                *(bf16x8*)&As[row][col8] = *(bf16x8*)tmp;
            } else {
                const short* A = (const short*)Av;
                *(bf16x8*)&As[row][col8] = *(const bf16x8*)&A[(size_t)(m0 + row) * 512 + kt + col8];
            }
            *(bf16x8*)&Bs[row][col8] = *(const bf16x8*)&Bt[(size_t)(n0 + row) * 512 + kt + col8];
        }
        __syncthreads();
#pragma unroll
        for (int kb = 0; kb < 2; kb++) {
            int ko = kb * 32 + l4 * 8;
            bf16x8 af[4], bf[4];
#pragma unroll
            for (int t = 0; t < 4; t++) {
                af[t] = *(const bf16x8*)&As[wm * 64 + t * 16 + l15][ko];
                bf[t] = *(const bf16x8*)&Bs[wn * 64 + t * 16 + l15][ko];
            }
#pragma unroll
            for (int mt = 0; mt < 4; mt++)
#pragma unroll
                for (int nt = 0; nt < 4; nt++)
                    acc[mt][nt] = mfma16(af[mt], bf[nt], acc[mt][nt]);
        }
    }
#pragma unroll
    for (int mt = 0; mt < 4; mt++)
#pragma unroll
        for (int nt = 0; nt < 4; nt++) {
            f32x4 vv = acc[mt][nt];
            int col = n0 + wn * 64 + nt * 16 + l15;
            float bv = bias[col];
#pragma unroll
            for (int r = 0; r < 4; r++) {
                int row = m0 + wm * 64 + mt * 16 + l4 * 4 + r;
                float val = vv[r] + bv;
                if (VT) {
                    int b = row >> 12, j = row & 4095;
                    ((short*)C)[(size_t)b * (ND * NN) + (size_t)col * NN + j] = f2bf(val);
                } else if (OF32) {
                    ((float*)C)[(size_t)row * 512 + col] = val;
                } else {
                    ((short*)C)[(size_t)row * 512 + col] = f2bf(val);
                }
            }
        }
}

// ---------------- flash attention v4: key-split, LDS-staged, 2 blocks/CU --------
// Block: 64 q-rows x 2048 keys (kh half), 512 thr (8 waves). Tk=32, 64 chunks.
// Waves: wr=w&1 (32 q-rows), wq=w>>1 (QK: k-quarter 128; PV: e-group 64 per phase).
// S = sum of 4 k-quarter partials via LDS atomicAdd (zeroed in softmax read-out).
// PV in two 256-e phases sharing one V buffer. 5 __syncthreads per chunk.
// Output: normalized-by-local-l O~ (bf16) + per-row (m,l) for the merge kernel.
__global__ __launch_bounds__(512, 4) void flash_attn_ks(
    const short* __restrict__ qp, const short* __restrict__ kp,
    const short* __restrict__ vpT, short* __restrict__ Opart,
    float* __restrict__ mlm, float* __restrict__ mll) {
    __shared__ short bufK[32 * 520];   // 32 keys x 512 k, row stride 520 (16B-mult, %32w=4)
    __shared__ short bufV[256 * 40];   // 256 e x 32 j, row stride 40 (16B-mult)
    __shared__ float Sld[64 * 33];     // 64 q x 32 keys fp32, stride 33 (odd)
    __shared__ short Pld[64 * 40];     // 64 q x 32 keys bf16
    __shared__ float mrow[64], lrow[64], arow[64];

    int tid = threadIdx.x;
    int lane = tid & 63, w = tid >> 6;
    int l15 = lane & 15, l4 = lane >> 4;
    int wr = w & 1;    // q half: rows wr*32 .. +31
    int wq = w >> 1;   // 0..3
    int b = blockIdx.y, kh = blockIdx.z;
    int q0 = blockIdx.x * 64;
    int key0 = kh * 2048;

    const short* qpb = qp + (size_t)b * (NN * ND);
    const short* kpb = kp + (size_t)b * (NN * ND);
    const short* vtb = vpT + (size_t)b * (ND * NN);

    // Q frags: rows q0+wr*32+p*16+l15, k = wq*128 + i*32 + l4*8 (32 VGPR)
    bf16x8 qf[2][4];
#pragma unroll
    for (int p = 0; p < 2; p++)
#pragma unroll
        for (int i = 0; i < 4; i++)
            qf[p][i] = *(const bf16x8*)&qpb[(size_t)(q0 + wr * 32 + p * 16 + l15) * ND +
                                            wq * 128 + i * 32 + l4 * 8];

    for (int i = tid; i < 64 * 33; i += 512) Sld[i] = 0.f;
    if (tid < 64) { mrow[tid] = -1e30f; lrow[tid] = 0.f; }

    // stage K(0): 32 rows x 512
#pragma unroll
    for (int t = 0; t < 4; t++) {
        int u = tid + t * 512;
        int r = u >> 6, c8 = (u & 63) * 8;
        *(bf16x8*)&bufK[r * 520 + c8] = *(const bf16x8*)&kpb[(size_t)(key0 + r) * ND + c8];
    }
    __syncthreads();   // A(0)

    f32x4 oacc[2][8] = {};

    for (int j = 0; j < 64; j++) {
        int j0 = key0 + j * 32;
        bool havK = (j < 63);
        // ---- QK: issue V-phase0 loads, MFMA on bufK, atomicAdd partial S ----
        bf16x8 v0t[2];
#pragma unroll
        for (int t = 0; t < 2; t++) {
            int u = tid + t * 512;
            int e = u >> 2, c8 = (u & 3) * 8;
            v0t[t] = *(const bf16x8*)&vtb[(size_t)e * NN + j0 + c8];
        }
#pragma unroll
        for (int kt = 0; kt < 2; kt++) {
            f32x4 s0 = {}, s1 = {};
#pragma unroll
            for (int i = 0; i < 4; i++) {
                bf16x8 kf = *(const bf16x8*)&bufK[(kt * 16 + l15) * 520 + wq * 128 + i * 32 + l4 * 8];
                s0 = mfma16(qf[0][i], kf, s0);
                s1 = mfma16(qf[1][i], kf, s1);
            }
#pragma unroll
            for (int r = 0; r < 4; r++) {
                atomicAdd(&Sld[(wr * 32 + l4 * 4 + r) * 33 + kt * 16 + l15], s0[r]);
                atomicAdd(&Sld[(wr * 32 + 16 + l4 * 4 + r) * 33 + kt * 16 + l15], s1[r]);
            }
        }
#pragma unroll
        for (int t = 0; t < 2; t++) {
            int u = tid + t * 512;
            int e = u >> 2, c8 = (u & 3) * 8;
            *(bf16x8*)&bufV[e * 40 + c8] = v0t[t];
        }
        __syncthreads();   // B: S complete, V-phase0 staged
        // ---- softmax (reads+zeroes S, writes P) + K(j+1) pair-A loads ----
        bf16x8 kA[2];
        if (havK) {
#pragma unroll
            for (int t = 0; t < 2; t++) {
                int u = tid + t * 512;
                int r = u >> 6, c8 = (u & 63) * 8;
                kA[t] = *(const bf16x8*)&kpb[(size_t)(j0 + 32 + r) * ND + c8];
            }
        }
        {
            int row = tid >> 3, c = tid & 7;
            float v[4];
            float mx = -1e30f;
#pragma unroll
            for (int i = 0; i < 4; i++) {
                int idx = row * 33 + c * 4 + i;
                v[i] = Sld[idx] * 0.125f;
                Sld[idx] = 0.f;
                mx = fmaxf(mx, v[i]);
            }
#pragma unroll
            for (int off = 1; off < 8; off <<= 1) mx = fmaxf(mx, __shfl_xor(mx, off));
            float mo = mrow[row];
            float mn = fmaxf(mo, mx);
            float ps = 0.f;
#pragma unroll
            for (int i = 0; i < 4; i++) { v[i] = __expf(v[i] - mn); ps += v[i]; }
#pragma unroll
            for (int off = 1; off < 8; off <<= 1) ps += __shfl_xor(ps, off);
            float al = __expf(mo - mn);
            if (c == 0) { mrow[row] = mn; lrow[row] = lrow[row] * al + ps; arow[row] = al; }
            short4 tmp;
            tmp.x = f2bf(v[0]); tmp.y = f2bf(v[1]); tmp.z = f2bf(v[2]); tmp.w = f2bf(v[3]);
            *(short4*)&Pld[row * 40 + c * 4] = tmp;
        }
        __syncthreads();   // C: P/arow ready, S zeroed
        // ---- PV phase 0 + K(j+1) LDS writes ----
        if (havK) {
#pragma unroll
            for (int t = 0; t < 2; t++) {
                int u = tid + t * 512;
                int r = u >> 6, c8 = (u & 63) * 8;
                *(bf16x8*)&bufK[r * 520 + c8] = kA[t];
            }
        }
        bf16x8 kB[2];
        if (havK) {
#pragma unroll
            for (int t = 0; t < 2; t++) {
                int u = tid + (2 + t) * 512;
                int r = u >> 6, c8 = (u & 63) * 8;
                kB[t] = *(const bf16x8*)&kpb[(size_t)(j0 + 32 + r) * ND + c8];
            }
        }
        float al2[2][4];
#pragma unroll
        for (int p = 0; p < 2; p++)
#pragma unroll
            for (int r = 0; r < 4; r++) al2[p][r] = arow[wr * 32 + p * 16 + l4 * 4 + r];
#pragma unroll
        for (int p = 0; p < 2; p++)
#pragma unroll
            for (int et = 0; et < 8; et++)
#pragma unroll
                for (int r = 0; r < 4; r++) oacc[p][et][r] *= al2[p][r];
        bf16x8 pa[2];
#pragma unroll
        for (int p = 0; p < 2; p++)
            pa[p] = *(const bf16x8*)&Pld[(wr * 32 + p * 16 + l15) * 40 + l4 * 8];
#pragma unroll
        for (int tt = 0; tt < 4; tt++) {
            bf16x8 vf = *(const bf16x8*)&bufV[(wq * 64 + tt * 16 + l15) * 40 + l4 * 8];
            oacc[0][tt] = mfma16(pa[0], vf, oacc[0][tt]);
            oacc[1][tt] = mfma16(pa[1], vf, oacc[1][tt]);
        }
        if (havK) {
#pragma unroll
            for (int t = 0; t < 2; t++) {
                int u = tid + (2 + t) * 512;
                int r = u >> 6, c8 = (u & 63) * 8;
                *(bf16x8*)&bufK[r * 520 + c8] = kB[t];
            }
        }
        __syncthreads();   // D: V-phase0 reads done, K(j+1) staged
        // ---- V phase 1 stage ----
#pragma unroll
        for (int t = 0; t < 2; t++) {
            int u = tid + t * 512;
            int e = u >> 2, c8 = (u & 3) * 8;
            *(bf16x8*)&bufV[e * 40 + c8] = *(const bf16x8*)&vtb[(size_t)(256 + e) * NN + j0 + c8];
        }
        __syncthreads();   // E: V-phase1 staged
        // ---- PV phase 1 ----
#pragma unroll
        for (int tt = 0; tt < 4; tt++) {
            bf16x8 vf = *(const bf16x8*)&bufV[(wq * 64 + tt * 16 + l15) * 40 + l4 * 8];
            oacc[0][4 + tt] = mfma16(pa[0], vf, oacc[0][4 + tt]);
            oacc[1][4 + tt] = mfma16(pa[1], vf, oacc[1][4 + tt]);
        }
        __syncthreads();   // A(j+1): V-phase1 reads done -> bufV reusable
    }
    // ---- epilogue: O~ = O/l_local (bf16) + (m,l) per row ----
    if (tid < 64) {
        size_t ri = (size_t)kh * (NB * NN) + (size_t)b * NN + q0 + tid;
        mlm[ri] = mrow[tid];
        mll[ri] = lrow[tid];
    }
    float li[2][4];
#pragma unroll
    for (int p = 0; p < 2; p++)
#pragma unroll
        for (int r = 0; r < 4; r++) li[p][r] = 1.f / lrow[wr * 32 + p * 16 + l4 * 4 + r];
    short* opb = Opart + ((size_t)kh * NB + b) * (NN * ND);
#pragma unroll
    for (int p = 0; p < 2; p++)
#pragma unroll
        for (int et = 0; et < 8; et++) {
            int e = (et >> 2) * 256 + wq * 64 + (et & 3) * 16 + l15;
#pragma unroll
            for (int r = 0; r < 4; r++) {
                int row = q0 + wr * 32 + p * 16 + l4 * 4 + r;
                opb[(size_t)row * ND + e] = f2bf(oacc[p][et][r] * li[p][r]);
            }
        }
}

// ---------------- merge the two key-half partials -> dpa (bf16) ----------------
__global__ __launch_bounds__(256) void merge_halves(
    const short* __restrict__ Opart, const float* __restrict__ mlm,
    const float* __restrict__ mll, short* __restrict__ dpa) {
    int gid = blockIdx.x * 256 + threadIdx.x;   // 1048576 threads, 8 elems each
    int R = gid >> 6;                            // flat row in [0, NB*NN)
    int e8 = (gid & 63) * 8;
    float m0 = mlm[R], m1 = mlm[NB * NN + R];
    float l0 = mll[R], l1 = mll[NB * NN + R];
    float M = fmaxf(m0, m1);
    float a0 = l0 * __expf(m0 - M), a1 = l1 * __expf(m1 - M);
    float inv = 1.f / (a0 + a1);
    float w0 = a0 * inv, w1 = a1 * inv;
    bf16x8 O0 = *(const bf16x8*)&Opart[(size_t)R * ND + e8];
    bf16x8 O1 = *(const bf16x8*)&Opart[(size_t)(NB * NN) * ND + (size_t)R * ND + e8];
    short out[8];
#pragma unroll
    for (int i = 0; i < 8; i++)
        out[i] = f2bf(w0 * bf2f(O0[i]) + w1 * bf2f(O1[i]));
    *(bf16x8*)&dpa[(size_t)R * ND + e8] = *(bf16x8*)out;
}

extern "C" void kernel_launch(void* const* d_in, const int* in_sizes, int n_in,
                              void* d_out, int out_size, void* d_ws, size_t ws_size,
                              hipStream_t stream) {
    const float* q     = (const float*)d_in[0];
    const float* k     = (const float*)d_in[1];
    const float* v     = (const float*)d_in[2];
    const float* w_q   = (const float*)d_in[3];
    const float* w_k   = (const float*)d_in[4];
    const float* w_v   = (const float*)d_in[5];
    const float* w_mha = (const float*)d_in[6];
    const float* b_q   = (const float*)d_in[7];
    const float* b_k   = (const float*)d_in[8];
    const float* b_v   = (const float*)d_in[9];
    const float* b_mha = (const float*)d_in[10];

    const size_t T = (size_t)NB * NN * ND;  // 8388608
    short* ws    = (short*)d_ws;
    short* qp    = ws;
    short* kp    = qp + T;
    short* vpT   = kp + T;
    short* dpa   = vpT + T;
    short* Wt    = dpa + T;              // 4 * 262144 shorts
    short* Opart = Wt + 1048576;         // 2 * T shorts (33.5 MB)
    float* mlm   = (float*)(Opart + 2 * T);   // 2 * NB*NN floats
    float* mll   = mlm + 2 * NB * NN;

    Ptrs4 p;
    p.in[0] = w_q;   p.out[0] = Wt;
    p.in[1] = w_k;   p.out[1] = Wt + 262144;
    p.in[2] = w_v;   p.out[2] = Wt + 524288;
    p.in[3] = w_mha; p.out[3] = Wt + 786432;
    transpose_w<<<dim3(16, 16, 4), dim3(32, 8), 0, stream>>>(p);

    gemm_bt_bias<1, 0, 0><<<dim3(4, 128), 256, 0, stream>>>(q, Wt,          b_q, qp);
    gemm_bt_bias<1, 0, 0><<<dim3(4, 128), 256, 0, stream>>>(k, Wt + 262144, b_k, kp);
    gemm_bt_bias<1, 1, 0><<<dim3(4, 128), 256, 0, stream>>>(v, Wt + 524288, b_v, vpT);

    flash_attn_ks<<<dim3(64, 4, 2), 512, 0, stream>>>(qp, kp, vpT, Opart, mlm, mll);
    merge_halves<<<4096, 256, 0, stream>>>(Opart, mlm, mll, dpa);

    gemm_bt_bias<0, 0, 1><<<dim3(4, 128), 256, 0, stream>>>(dpa, Wt + 786432, b_mha, d_out);
}